// Round 12
// baseline (224.405 us; speedup 1.0000x reference)
//
#include <hip/hip_runtime.h>
#include <math.h>

#define T_BINS 350
#define REF_LEN 32
#define NB 32
#define NPIX 3072
#define N1 240
#define N2 10
#define NVAL 256
#define SEG1 182              // 13*14
#define SEG2 168              // 12*14

// ---------------------------------------------------------------------------
// Kernel 1 (fused): blocks 0..31 -> per-batch CSR build; blocks 32..223 ->
// 64x64 tiled transpose of w1; block 224 -> inverse bin map inv[t]=v or -1.
// ---------------------------------------------------------------------------
__global__ void prep(const int* __restrict__ inp,
                     int* __restrict__ pix,    // [NB][NPIX]
                     int* __restrict__ offs,   // [NB][NVAL]
                     int* __restrict__ cnts,   // [NB][NVAL]
                     const float* __restrict__ w1,
                     float* __restrict__ w1t,
                     const int* __restrict__ table,
                     int* __restrict__ inv)    // [T_BINS]
{
    __shared__ int lc[NVAL];
    __shared__ int ls[NVAL];
    __shared__ int lslot[NVAL];
    __shared__ float tile[64][65];
    __shared__ int linv[T_BINS];

    const int tid = threadIdx.x;

    if (blockIdx.x < NB) {
        // ---- CSR build for batch b ----
        const int b = blockIdx.x;
        lc[tid] = 0;
        __syncthreads();

        int vals[12];
        #pragma unroll
        for (int i = 0; i < 12; ++i) {
            int v = inp[b * NPIX + i * 256 + tid];   // coalesced
            vals[i] = v;
            atomicAdd(&lc[v], 1);
        }
        __syncthreads();

        int x = lc[tid];
        ls[tid] = x;
        __syncthreads();
        for (int d = 1; d < 256; d <<= 1) {
            int y = (tid >= d) ? ls[tid - d] : 0;
            __syncthreads();
            ls[tid] += y;
            __syncthreads();
        }
        int excl = ls[tid] - x;
        offs[b * NVAL + tid] = excl;
        cnts[b * NVAL + tid] = x;
        lslot[tid] = excl;
        __syncthreads();

        #pragma unroll
        for (int i = 0; i < 12; ++i) {
            int slot = atomicAdd(&lslot[vals[i]], 1);
            pix[b * NPIX + slot] = i * 256 + tid;
        }
    } else if (blockIdx.x < NB + 192) {
        // ---- transpose tile ----
        const int tt = blockIdx.x - NB;       // 0..191
        const int p0 = (tt % 48) * 64;
        const int n0 = (tt / 48) * 64;
        const int c  = tid & 63;
        const int r0 = tid >> 6;              // 0..3

        #pragma unroll
        for (int i = 0; i < 16; ++i) {
            int n = n0 + r0 + i * 4;
            if (n < N1) tile[r0 + i * 4][c] = w1[n * NPIX + p0 + c];
        }
        __syncthreads();
        #pragma unroll
        for (int i = 0; i < 16; ++i) {
            int p = p0 + r0 + i * 4;
            int n = n0 + c;
            if (n < N1) w1t[p * N1 + n] = tile[c][r0 + i * 4];
        }
    } else {
        // ---- inverse bin map (table is injective value->bin) ----
        for (int i = tid; i < T_BINS; i += 256) linv[i] = -1;
        __syncthreads();
        if (tid < NVAL) linv[table[tid]] = tid;
        __syncthreads();
        for (int i = tid; i < T_BINS; i += 256) inv[i] = linv[i];
    }
}

// ---------------------------------------------------------------------------
// Dynamics math:
//   PSP alpha-kernel exact IIR:  q=A(q+p); p=Ap+u; y=(e/10)q   A=e^-0.1
//   Truncated 32-tap refractory exact IIR (Ar=e^-1) with expiry corrections
//   from bits 30/31 of the spike-history mask.
// ---------------------------------------------------------------------------
#define DYN_CONSTS \
    const double A    = 0.9048374180359595;     \
    const double C    = 0.2718281828459045;     \
    const double Ar   = 0.36787944117144233;    \
    const double Cr   = -54.365636569180904;    \
    const double C31A = 1.0671679036256927e-12; \
    const double C31B = 3.4424771084699765e-14;

#define DYN_CORE(uin)                                         \
        q = A * (q + p);                                      \
        p = A * p + (uin);                                    \
        double vm = C * q + Cr * Q;                           \
        unsigned int sb = (vm >= 10.0) ? 1u : 0u;             \
        double s = (double)sb;                                \
        double sel31 = (hist & 0x80000000u) ? C31A : 0.0;     \
        double sel30 = (hist & 0x40000000u) ? C31B : 0.0;     \
        Q = Ar * (Q + P - sel31);                             \
        P = s + (Ar * P - sel30);                             \
        hist = (hist << 1) | sb;

// ---------------------------------------------------------------------------
// Kernel 2 (fused u1 + layer-1 dynamics): 128 blocks = (b, 64-wide n-tile),
// 256 threads = 4 waves. Two time segments (182 + 168 bins) through a 46.6 KB
// LDS buffer:
//   A-phase (all 4 waves): gather u1 for the segment's bins into LDS
//     (fp64 acc, ascending pixel order, single fp32 rounding -> bit-identical
//      values to R8's u1t path; wave-uniform CSR lookups -> scalar loads).
//   B-phase (wave 0): 14-deep chunked dynamics from LDS, IIR+refractory state
//     carried in registers across segments; one u64 ballot mask per step.
// Lanes with n>=N1 get u=0 -> never spike -> ballot bit 0 (same as R8).
// ---------------------------------------------------------------------------
__global__ __launch_bounds__(256) void l1_fused(
                     const float* __restrict__ w1t,   // [NPIX][N1]
                     const int* __restrict__ pix,
                     const int* __restrict__ offs,
                     const int* __restrict__ cnts,
                     const int* __restrict__ inv,     // [T_BINS]
                     unsigned long long* __restrict__ s1m) // [NB][T][4]
{
    __shared__ float lu1[SEG1 * 64];    // 46.6 KB (SEG2 < SEG1 reuses it)
    const int tid  = threadIdx.x;
    const int lane = tid & 63;
    const int wv   = tid >> 6;          // 0..3
    const int b    = blockIdx.x >> 2;
    const int k    = blockIdx.x & 3;
    const int n    = k * 64 + lane;
    const int nn   = (n < N1) ? n : 0;  // clamped load index (no OOB)
    const bool valid = (n < N1);

    unsigned long long* mp = s1m + (size_t)b * T_BINS * 4 + k;

    DYN_CONSTS
    double p = 0.0, q = 0.0, P = 0.0, Q = 0.0;
    unsigned int hist = 0u;

    for (int seg = 0; seg < 2; ++seg) {
        const int lo  = (seg == 0) ? 0 : SEG1;
        const int len = (seg == 0) ? SEG1 : SEG2;

        // ---- A-phase: gather this segment's u1 into LDS ----
        for (int t = lo + wv; t < lo + len; t += 4) {   // wave-uniform t
            const int v = inv[t];
            double acc = 0.0;
            if (v >= 0) {
                const int cnt = cnts[b * NVAL + v];
                const int* pl = pix + b * NPIX + offs[b * NVAL + v];
                int i = 0;
                for (; i + 4 <= cnt; i += 4) {
                    int p0 = pl[i], p1 = pl[i + 1], p2 = pl[i + 2], p3 = pl[i + 3];
                    double w0  = (double)w1t[p0 * N1 + nn];
                    double w1v = (double)w1t[p1 * N1 + nn];
                    double w2v = (double)w1t[p2 * N1 + nn];
                    double w3  = (double)w1t[p3 * N1 + nn];
                    acc += w0; acc += w1v; acc += w2v; acc += w3;  // ascending
                }
                for (; i < cnt; ++i)
                    acc += (double)w1t[pl[i] * N1 + nn];
            }
            lu1[(t - lo) * 64 + lane] = valid ? (float)acc : 0.0f;
        }
        __syncthreads();

        // ---- B-phase: wave 0 runs the dynamics for this segment ----
        if (wv == 0) {
            for (int c = 0; c < len; c += 14) {
                double cb[14];
                #pragma unroll
                for (int i = 0; i < 14; ++i)
                    cb[i] = (double)lu1[(c + i) * 64 + lane];
                #pragma unroll
                for (int i = 0; i < 14; ++i) {
                    DYN_CORE(cb[i])
                    unsigned long long msk = __ballot(sb != 0u);
                    if (lane == 0) mp[(size_t)(lo + c + i) * 4] = msk;
                }
            }
        }
        __syncthreads();   // protect LDS reuse by segment 2's A-phase
    }
}

// ---------------------------------------------------------------------------
// Kernel 3: u2[b,t,m] = sum over set spike bits of w2[m,n], ascending n
// (skipping exact-0.0 terms is IEEE-identical). fp64 acc, fp32 store.
// Exactly R8's version (known-good 149.7 µs configuration).
// ---------------------------------------------------------------------------
__global__ void compute_u2(const unsigned long long* __restrict__ s1m, // [NB][T][4]
                           const float* __restrict__ w2,   // [N2][N1]
                           float* __restrict__ u2)         // [NB][T][N2]
{
    __shared__ float lw2[N2][N1];   // 9.6 KB
    const int tid = threadIdx.x;
    for (int i = tid; i < N2 * N1; i += 256) lw2[i / N1][i % N1] = w2[i];
    __syncthreads();

    int id = blockIdx.x * 256 + tid;
    if (id >= NB * T_BINS * N2) return;
    int bt = id / N2;
    int m  = id - bt * N2;
    const unsigned long long* mp = s1m + (size_t)bt * 4;

    double acc = 0.0;
    #pragma unroll
    for (int kk = 0; kk < 4; ++kk) {
        unsigned long long msk = mp[kk];
        while (msk) {
            int j = __ffsll(msk) - 1;
            acc += (double)lw2[m][kk * 64 + j];
            msk &= msk - 1;
        }
    }
    u2[id] = (float)acc;
}

// ---------------------------------------------------------------------------
// Kernel 4: layer-2 dynamics, one thread per (b,m); writes [B][N2][T].
// Exactly R8's version.
// ---------------------------------------------------------------------------
__global__ void layer2_dyn(const float* __restrict__ u2,   // [NB][T][N2]
                           float* __restrict__ out)        // [NB][N2][T]
{
    const int id = blockIdx.x * 64 + threadIdx.x;
    if (id >= NB * N2) return;
    const int b = id / N2;
    const int m = id - b * N2;
    const float* up = u2 + (size_t)b * T_BINS * N2 + m;
    float*       op = out + ((size_t)b * N2 + m) * T_BINS;

    DYN_CONSTS
    double p = 0.0, q = 0.0, P = 0.0, Q = 0.0;
    unsigned int hist = 0u;

    double cb[14], nb[14];
    #pragma unroll
    for (int i = 0; i < 14; ++i) cb[i] = (double)up[(size_t)i * N2];

    for (int t0 = 0; t0 < T_BINS; t0 += 14) {
        if (t0 + 14 < T_BINS) {
            #pragma unroll
            for (int i = 0; i < 14; ++i)
                nb[i] = (double)up[(size_t)(t0 + 14 + i) * N2];
        }
        #pragma unroll
        for (int i = 0; i < 14; ++i) {
            DYN_CORE(cb[i])
            op[t0 + i] = (float)s;
        }
        #pragma unroll
        for (int i = 0; i < 14; ++i) cb[i] = nb[i];
    }
}

// ---------------------------------------------------------------------------
extern "C" void kernel_launch(void* const* d_in, const int* in_sizes, int n_in,
                              void* d_out, int out_size, void* d_ws, size_t ws_size,
                              hipStream_t stream) {
    const int*   inp   = (const int*)d_in[0];    // [32,3,32,32]
    const int*   table = (const int*)d_in[1];    // [256]
    const float* w1    = (const float*)d_in[2];  // [240,3072]
    const float* w2    = (const float*)d_in[3];  // [10,240]
    float* out = (float*)d_out;                  // [32,10,350]

    char* ws = (char*)d_ws;
    size_t off = 0;
    float* w1t = (float*)(ws + off);  off += (size_t)NPIX * N1 * 4;          // 2.9 MB
    float* u2  = (float*)(ws + off);  off += (size_t)NB * T_BINS * N2 * 4;   // 448 KB
    unsigned long long* s1m = (unsigned long long*)(ws + off);
    off += (size_t)NB * T_BINS * 4 * 8;                                      // 358 KB
    int*   pix = (int*)(ws + off);    off += (size_t)NB * NPIX * 4;
    int*  offs = (int*)(ws + off);    off += (size_t)NB * NVAL * 4;
    int*  cnts = (int*)(ws + off);    off += (size_t)NB * NVAL * 4;
    int*   inv = (int*)(ws + off);    off += (size_t)T_BINS * 4;

    prep<<<NB + 192 + 1, 256, 0, stream>>>(inp, pix, offs, cnts, w1, w1t, table, inv);
    l1_fused<<<NB * 4, 256, 0, stream>>>(w1t, pix, offs, cnts, inv, s1m);
    compute_u2<<<(NB * T_BINS * N2 + 255) / 256, 256, 0, stream>>>(s1m, w2, u2);
    layer2_dyn<<<(NB * N2 + 63) / 64, 64, 0, stream>>>(u2, out);
}

// Round 13
// 150.302 us; speedup vs baseline: 1.4930x; 1.4930x over previous
//
#include <hip/hip_runtime.h>
#include <math.h>

#define T_BINS 350
#define REF_LEN 32
#define NB 32
#define NPIX 3072
#define N1 240
#define N2 10
#define NVAL 256

// ---------------------------------------------------------------------------
// Kernel 1 (fused): blocks 0..31 -> per-batch CSR build; blocks 32..223 ->
// 64x64 tiled transpose of w1; block 224 -> inverse bin map inv[t]=v or -1.
// ---------------------------------------------------------------------------
__global__ void prep(const int* __restrict__ inp,
                     int* __restrict__ pix,    // [NB][NPIX]
                     int* __restrict__ offs,   // [NB][NVAL]
                     int* __restrict__ cnts,   // [NB][NVAL]
                     const float* __restrict__ w1,
                     float* __restrict__ w1t,
                     const int* __restrict__ table,
                     int* __restrict__ inv)    // [T_BINS]
{
    __shared__ int lc[NVAL];
    __shared__ int ls[NVAL];
    __shared__ int lslot[NVAL];
    __shared__ float tile[64][65];
    __shared__ int linv[T_BINS];

    const int tid = threadIdx.x;

    if (blockIdx.x < NB) {
        // ---- CSR build for batch b ----
        const int b = blockIdx.x;
        lc[tid] = 0;
        __syncthreads();

        int vals[12];
        #pragma unroll
        for (int i = 0; i < 12; ++i) {
            int v = inp[b * NPIX + i * 256 + tid];   // coalesced
            vals[i] = v;
            atomicAdd(&lc[v], 1);
        }
        __syncthreads();

        int x = lc[tid];
        ls[tid] = x;
        __syncthreads();
        for (int d = 1; d < 256; d <<= 1) {
            int y = (tid >= d) ? ls[tid - d] : 0;
            __syncthreads();
            ls[tid] += y;
            __syncthreads();
        }
        int excl = ls[tid] - x;
        offs[b * NVAL + tid] = excl;
        cnts[b * NVAL + tid] = x;
        lslot[tid] = excl;
        __syncthreads();

        #pragma unroll
        for (int i = 0; i < 12; ++i) {
            int slot = atomicAdd(&lslot[vals[i]], 1);
            pix[b * NPIX + slot] = i * 256 + tid;
        }
    } else if (blockIdx.x < NB + 192) {
        // ---- transpose tile ----
        const int tt = blockIdx.x - NB;       // 0..191
        const int p0 = (tt % 48) * 64;
        const int n0 = (tt / 48) * 64;
        const int c  = tid & 63;
        const int r0 = tid >> 6;              // 0..3

        #pragma unroll
        for (int i = 0; i < 16; ++i) {
            int n = n0 + r0 + i * 4;
            if (n < N1) tile[r0 + i * 4][c] = w1[n * NPIX + p0 + c];
        }
        __syncthreads();
        #pragma unroll
        for (int i = 0; i < 16; ++i) {
            int p = p0 + r0 + i * 4;
            int n = n0 + c;
            if (n < N1) w1t[p * N1 + n] = tile[c][r0 + i * 4];
        }
    } else {
        // ---- inverse bin map (table is injective value->bin) ----
        for (int i = tid; i < T_BINS; i += 256) linv[i] = -1;
        __syncthreads();
        if (tid < NVAL) linv[table[tid]] = tid;
        __syncthreads();
        for (int i = tid; i < T_BINS; i += 256) inv[i] = linv[i];
    }
}

// ---------------------------------------------------------------------------
// Kernel 2: u1t[b][t][n] = sum over pixels with value inv[t] of w1t[p, n];
// zero when bin empty. fp64 accumulate (ascending order), single fp32
// rounding on store.
// ---------------------------------------------------------------------------
__global__ void compute_u1(const float* __restrict__ w1t,
                           const int* __restrict__ pix,
                           const int* __restrict__ offs,
                           const int* __restrict__ cnts,
                           const int* __restrict__ inv,
                           float* __restrict__ u1t)   // [NB][T_BINS][N1]
{
    const int t = blockIdx.x;
    const int b = blockIdx.y;
    const int tid = threadIdx.x;
    if (tid >= N1) return;
    const int v = inv[t];                    // block-uniform

    double acc = 0.0;
    if (v >= 0) {
        const int cnt = cnts[b * NVAL + v];
        const int* pl = pix + b * NPIX + offs[b * NVAL + v];
        int i = 0;
        for (; i + 4 <= cnt; i += 4) {
            int p0 = pl[i], p1 = pl[i + 1], p2 = pl[i + 2], p3 = pl[i + 3];
            double w0 = (double)w1t[p0 * N1 + tid];
            double w1v = (double)w1t[p1 * N1 + tid];
            double w2v = (double)w1t[p2 * N1 + tid];
            double w3 = (double)w1t[p3 * N1 + tid];
            acc += w0; acc += w1v; acc += w2v; acc += w3;   // ascending order
        }
        for (; i < cnt; ++i)
            acc += (double)w1t[pl[i] * N1 + tid];
    }
    u1t[((size_t)b * T_BINS + t) * N1 + tid] = (float)acc;
}

// ---------------------------------------------------------------------------
// Dynamics math:
//   PSP alpha-kernel exact IIR:  q=A(q+p); p=Ap+u; y=(e/10)q   A=e^-0.1
//   Truncated 32-tap refractory exact IIR (Ar=e^-1) with expiry corrections
//   from bits 30/31 of the spike-history mask.
// ---------------------------------------------------------------------------
#define DYN_CONSTS \
    const double A    = 0.9048374180359595;     \
    const double C    = 0.2718281828459045;     \
    const double Ar   = 0.36787944117144233;    \
    const double Cr   = -54.365636569180904;    \
    const double C31A = 1.0671679036256927e-12; \
    const double C31B = 3.4424771084699765e-14;

#define DYN_CORE(uin)                                         \
        q = A * (q + p);                                      \
        p = A * p + (uin);                                    \
        double vm = C * q + Cr * Q;                           \
        unsigned int sb = (vm >= 10.0) ? 1u : 0u;             \
        double s = (double)sb;                                \
        double sel31 = (hist & 0x80000000u) ? C31A : 0.0;     \
        double sel30 = (hist & 0x40000000u) ? C31B : 0.0;     \
        Q = Ar * (Q + P - sel31);                             \
        P = s + (Ar * P - sel30);                             \
        hist = (hist << 1) | sb;

// ---------------------------------------------------------------------------
// Kernel 3: layer-1 dynamics. 128 blocks x 64 threads (one wave each).
// fp32 streaming loads from dense u1t; 14-deep chunks (350 = 25*14).
// Spikes emitted as one u64 ballot per wave per step.
// ---------------------------------------------------------------------------
__global__ __launch_bounds__(64) void layer1_dyn(
                           const float* __restrict__ u1t,   // [NB][T][N1]
                           unsigned long long* __restrict__ s1m) // [NB][T][4]
{
    const int tid = threadIdx.x;             // 0..63
    const int b   = blockIdx.x >> 2;
    const int k   = blockIdx.x & 3;          // n-tile
    const int n   = k * 64 + tid;
    if (n >= N1) return;                     // tile 3 lanes 48..63: ballot bits 0

    const float* ub = u1t + (size_t)b * T_BINS * N1 + n;
    unsigned long long* mp = s1m + ((size_t)b * T_BINS) * 4 + k;

    DYN_CONSTS
    double p = 0.0, q = 0.0, P = 0.0, Q = 0.0;
    unsigned int hist = 0u;

    double cb[14], nb[14];
    #pragma unroll
    for (int i = 0; i < 14; ++i) cb[i] = (double)ub[(size_t)i * N1];

    for (int t0 = 0; t0 < T_BINS; t0 += 14) {
        if (t0 + 14 < T_BINS) {
            #pragma unroll
            for (int i = 0; i < 14; ++i)
                nb[i] = (double)ub[(size_t)(t0 + 14 + i) * N1];
        }
        #pragma unroll
        for (int i = 0; i < 14; ++i) {
            DYN_CORE(cb[i])
            unsigned long long msk = __ballot(sb != 0u);
            if (tid == 0) mp[(size_t)(t0 + i) * 4] = msk;
        }
        #pragma unroll
        for (int i = 0; i < 14; ++i) cb[i] = nb[i];
    }
}

// ---------------------------------------------------------------------------
// Kernel 4: u2[b,t,m] = sum over set spike bits of w2[m,n], ascending n
// (skipping exact-0.0 terms is IEEE-identical). fp64 acc, fp32 store.
// ---------------------------------------------------------------------------
__global__ void compute_u2(const unsigned long long* __restrict__ s1m, // [NB][T][4]
                           const float* __restrict__ w2,   // [N2][N1]
                           float* __restrict__ u2)         // [NB][T][N2]
{
    __shared__ float lw2[N2][N1];   // 9.6 KB
    const int tid = threadIdx.x;
    for (int i = tid; i < N2 * N1; i += 256) lw2[i / N1][i % N1] = w2[i];
    __syncthreads();

    int id = blockIdx.x * 256 + tid;
    if (id >= NB * T_BINS * N2) return;
    int bt = id / N2;
    int m  = id - bt * N2;
    const unsigned long long* mp = s1m + (size_t)bt * 4;

    double acc = 0.0;
    #pragma unroll
    for (int kk = 0; kk < 4; ++kk) {
        unsigned long long msk = mp[kk];
        while (msk) {
            int j = __ffsll(msk) - 1;
            acc += (double)lw2[m][kk * 64 + j];
            msk &= msk - 1;
        }
    }
    u2[id] = (float)acc;
}

// ---------------------------------------------------------------------------
// Kernel 5: layer-2 dynamics, one thread per (b,m); writes [B][N2][T].
// ---------------------------------------------------------------------------
__global__ void layer2_dyn(const float* __restrict__ u2,   // [NB][T][N2]
                           float* __restrict__ out)        // [NB][N2][T]
{
    const int id = blockIdx.x * 64 + threadIdx.x;
    if (id >= NB * N2) return;
    const int b = id / N2;
    const int m = id - b * N2;
    const float* up = u2 + (size_t)b * T_BINS * N2 + m;
    float*       op = out + ((size_t)b * N2 + m) * T_BINS;

    DYN_CONSTS
    double p = 0.0, q = 0.0, P = 0.0, Q = 0.0;
    unsigned int hist = 0u;

    double cb[14], nb[14];
    #pragma unroll
    for (int i = 0; i < 14; ++i) cb[i] = (double)up[(size_t)i * N2];

    for (int t0 = 0; t0 < T_BINS; t0 += 14) {
        if (t0 + 14 < T_BINS) {
            #pragma unroll
            for (int i = 0; i < 14; ++i)
                nb[i] = (double)up[(size_t)(t0 + 14 + i) * N2];
        }
        #pragma unroll
        for (int i = 0; i < 14; ++i) {
            DYN_CORE(cb[i])
            op[t0 + i] = (float)s;
        }
        #pragma unroll
        for (int i = 0; i < 14; ++i) cb[i] = nb[i];
    }
}

// ---------------------------------------------------------------------------
extern "C" void kernel_launch(void* const* d_in, const int* in_sizes, int n_in,
                              void* d_out, int out_size, void* d_ws, size_t ws_size,
                              hipStream_t stream) {
    const int*   inp   = (const int*)d_in[0];    // [32,3,32,32]
    const int*   table = (const int*)d_in[1];    // [256]
    const float* w1    = (const float*)d_in[2];  // [240,3072]
    const float* w2    = (const float*)d_in[3];  // [10,240]
    float* out = (float*)d_out;                  // [32,10,350]

    char* ws = (char*)d_ws;
    size_t off = 0;
    float* u1t = (float*)(ws + off);  off += (size_t)NB * T_BINS * N1 * 4;   // 10.75 MB
    float* u2  = (float*)(ws + off);  off += (size_t)NB * T_BINS * N2 * 4;   // 448 KB
    float* w1t = (float*)(ws + off);  off += (size_t)NPIX * N1 * 4;          // 2.9 MB
    unsigned long long* s1m = (unsigned long long*)(ws + off);
    off += (size_t)NB * T_BINS * 4 * 8;                                      // 358 KB
    int*   pix = (int*)(ws + off);    off += (size_t)NB * NPIX * 4;
    int*  offs = (int*)(ws + off);    off += (size_t)NB * NVAL * 4;
    int*  cnts = (int*)(ws + off);    off += (size_t)NB * NVAL * 4;
    int*   inv = (int*)(ws + off);    off += (size_t)T_BINS * 4;

    prep<<<NB + 192 + 1, 256, 0, stream>>>(inp, pix, offs, cnts, w1, w1t, table, inv);
    compute_u1<<<dim3(T_BINS, NB), 256, 0, stream>>>(w1t, pix, offs, cnts, inv, u1t);
    layer1_dyn<<<NB * 4, 64, 0, stream>>>(u1t, s1m);
    compute_u2<<<(NB * T_BINS * N2 + 255) / 256, 256, 0, stream>>>(s1m, w2, u2);
    layer2_dyn<<<(NB * N2 + 63) / 64, 64, 0, stream>>>(u2, out);
}